// Round 1
// baseline (208.766 us; speedup 1.0000x reference)
//
#include <hip/hip_runtime.h>
#include <hip/hip_bf16.h>
#include <stdint.h>

typedef __attribute__((ext_vector_type(8))) __bf16 bf16x8;
typedef __attribute__((ext_vector_type(4))) float f32x4;

#define B_   2
#define M_   4096
#define QH_  16
#define D_   192
#define N_   255
#define VD_  128

__global__ __launch_bounds__(256, 2) void cattn_kernel(
    const float* __restrict__ q, const float* __restrict__ k,
    const float* __restrict__ v, float* __restrict__ o_out,
    float* __restrict__ p_out)
{
    const float scale = 0.07216878364870322f; // 192^-0.5
    const int bid = blockIdx.x;
    const int ib  = bid & 63;          // q-block within head
    const int h   = (bid >> 6) & 15;
    const int b   = bid >> 10;
    const int i0  = ib << 6;

    const int tid  = threadIdx.x;
    const int lane = tid & 63;
    const int wid  = tid >> 6;
    const int g    = lane >> 4;   // quarter-wave group 0..3
    const int c16  = lane & 15;
    const int iw   = i0 + wid * 16;   // this wave's first q row

    // per-wave P staging buffer, bf16, stride 264 (=256+8) to break bank conflicts
    __shared__ __bf16 pbuf[4][16][264];

    // ---- load Q fragments (16 rows x 192), kept in regs for whole kernel
    // A-frag layout: a[e] = A[row = lane&15][kk = (lane>>4)*8 + e]
    bf16x8 aq[6];
    {
        const int qi = iw + c16;
        const float* qrow = q + ((size_t)((b * M_ + qi) * QH_ + h)) * D_;
        #pragma unroll
        for (int s = 0; s < 6; ++s) {
            const f32x4* qp = (const f32x4*)(qrow + s * 32 + g * 8);
            f32x4 q0 = qp[0], q1 = qp[1];
            bf16x8 a;
            a[0]=(__bf16)q0[0]; a[1]=(__bf16)q0[1]; a[2]=(__bf16)q0[2]; a[3]=(__bf16)q0[3];
            a[4]=(__bf16)q1[0]; a[5]=(__bf16)q1[1]; a[6]=(__bf16)q1[2]; a[7]=(__bf16)q1[3];
            aq[s] = a;
        }
    }

    // last n-tile with any unmasked element for this wave's rows
    // valid(i,n): i >= 16n+31 ; tile jt cols n in [16jt,16jt+15]
    int jt_any = (iw >= 16) ? ((iw - 16) >> 8) : -1;
    if (jt_any > 15) jt_any = 15;

    // ---- S = Q K^T  (16 x 255, tiled by 16 cols)
    f32x4 sacc[16];
    #pragma unroll
    for (int jt = 0; jt < 16; ++jt) {
        const int n = jt * 16 + c16;
        if (jt <= jt_any) {
            f32x4 acc = {0.f, 0.f, 0.f, 0.f};
            const int nn = (n < N_) ? n : (N_ - 1);  // clamp pad col 255
            const float* krow = k + ((size_t)((b * N_ + nn) * QH_ + h)) * D_;
            #pragma unroll
            for (int s = 0; s < 6; ++s) {
                const f32x4* kp = (const f32x4*)(krow + s * 32 + g * 8);
                f32x4 k0 = kp[0], k1 = kp[1];
                bf16x8 bb;
                bb[0]=(__bf16)k0[0]; bb[1]=(__bf16)k0[1]; bb[2]=(__bf16)k0[2]; bb[3]=(__bf16)k0[3];
                bb[4]=(__bf16)k1[0]; bb[5]=(__bf16)k1[1]; bb[6]=(__bf16)k1[2]; bb[7]=(__bf16)k1[3];
                acc = __builtin_amdgcn_mfma_f32_16x16x32_bf16(aq[s], bb, acc, 0, 0, 0);
            }
            // scale + causal mask; -1e30 so fully-masked rows -> uniform 1/255
            #pragma unroll
            for (int r = 0; r < 4; ++r) {
                const int i = iw + g * 4 + r;
                const bool ok = (i >= 16 * n + 31) && (n < N_);
                acc[r] = ok ? acc[r] * scale : -1e30f;
            }
            sacc[jt] = acc;
        } else {
            sacc[jt] = (f32x4){-1e30f, -1e30f, -1e30f, -1e30f};
        }
    }

    // ---- row softmax (row = iw + g*4 + r; reduce across 16 lanes of the group)
    float inv_l[4];
    #pragma unroll
    for (int r = 0; r < 4; ++r) {
        float m = sacc[0][r];
        #pragma unroll
        for (int jt = 1; jt < 16; ++jt) m = fmaxf(m, sacc[jt][r]);
        m = fmaxf(m, __shfl_xor(m, 1));
        m = fmaxf(m, __shfl_xor(m, 2));
        m = fmaxf(m, __shfl_xor(m, 4));
        m = fmaxf(m, __shfl_xor(m, 8));
        float sum = 0.f;
        #pragma unroll
        for (int jt = 0; jt < 16; ++jt) {
            float e = __expf(sacc[jt][r] - m);
            if (jt == 15 && c16 == 15) e = 0.f;   // col 255 doesn't exist
            sacc[jt][r] = e;                       // reuse as unnormalized p
            sum += e;
        }
        sum += __shfl_xor(sum, 1);
        sum += __shfl_xor(sum, 2);
        sum += __shfl_xor(sum, 4);
        sum += __shfl_xor(sum, 8);
        inv_l[r] = 1.0f / sum;
    }

    // ---- write p: fp32 to global, bf16 to LDS (all 16 tiles -> LDS fully init'd)
    #pragma unroll
    for (int jt = 0; jt < 16; ++jt) {
        const int n = jt * 16 + c16;
        #pragma unroll
        for (int r = 0; r < 4; ++r) {
            const int i = iw + g * 4 + r;
            const float pv = sacc[jt][r] * inv_l[r];
            if (n < N_) {
                p_out[(size_t)((b * QH_ + h) * M_ + i) * N_ + n] = pv;
            }
            pbuf[wid][g * 4 + r][jt * 16 + c16] = (__bf16)pv;
        }
    }

    __syncthreads();   // within-wave LDS write->read ordering (cheap, uniform)

    // ---- O = P V   (16 x 128), n-chunks of 32
    f32x4 oacc[8];
    #pragma unroll
    for (int t = 0; t < 8; ++t) oacc[t] = (f32x4){0.f, 0.f, 0.f, 0.f};

    const int c_lim = (jt_any < 0) ? 0 : ((jt_any + 2) >> 1);
    #pragma unroll
    for (int c = 0; c < 8; ++c) {
        if (c < c_lim) {
            // A-frag: P[row = c16][nn = c*32 + g*8 + e] from LDS (16B aligned)
            bf16x8 pa = *(const bf16x8*)(&pbuf[wid][c16][c * 32 + g * 8]);
            #pragma unroll
            for (int vdt = 0; vdt < 8; ++vdt) {
                bf16x8 vb;
                #pragma unroll
                for (int e = 0; e < 8; ++e) {
                    const int n = c * 32 + g * 8 + e;
                    const int nn = (n < N_) ? n : (N_ - 1);  // p(col 255)=0 nullifies
                    const float vv = v[((size_t)((b * N_ + nn) * QH_ + h)) * VD_ + vdt * 16 + c16];
                    vb[e] = (__bf16)vv;
                }
                oacc[vdt] = __builtin_amdgcn_mfma_f32_16x16x32_bf16(pa, vb, oacc[vdt], 0, 0, 0);
            }
        }
    }

    // ---- write O (rows < 31 forced to zero per reference)
    #pragma unroll
    for (int vdt = 0; vdt < 8; ++vdt) {
        #pragma unroll
        for (int r = 0; r < 4; ++r) {
            const int i = iw + g * 4 + r;
            const float val = (i < 31) ? 0.f : oacc[vdt][r];
            o_out[(size_t)((b * M_ + i) * QH_ + h) * VD_ + vdt * 16 + c16] = val;
        }
    }
}

extern "C" void kernel_launch(void* const* d_in, const int* in_sizes, int n_in,
                              void* d_out, int out_size, void* d_ws, size_t ws_size,
                              hipStream_t stream) {
    (void)in_sizes; (void)n_in; (void)d_ws; (void)ws_size; (void)out_size;
    const float* q = (const float*)d_in[0];
    const float* k = (const float*)d_in[1];
    const float* v = (const float*)d_in[2];
    float* o_out = (float*)d_out;
    float* p_out = o_out + (size_t)B_ * M_ * QH_ * VD_;   // tuple: (o, p) flat

    dim3 grid(B_ * QH_ * (M_ / 64));   // 2048 blocks: (b, h, 64-row q-block)
    dim3 block(256);                    // 4 waves x 16 rows
    cattn_kernel<<<grid, block, 0, stream>>>(q, k, v, o_out, p_out);
}

// Round 2
// 171.937 us; speedup vs baseline: 1.2142x; 1.2142x over previous
//
#include <hip/hip_runtime.h>
#include <hip/hip_bf16.h>
#include <stdint.h>

typedef __attribute__((ext_vector_type(8))) __bf16 bf16x8;
typedef __attribute__((ext_vector_type(4))) float f32x4;

#define B_   2
#define M_   4096
#define QH_  16
#define D_   192
#define N_   255
#define VD_  128
#define NP_  256   // padded n

// ---- pre-pass 1: kb[b][h][n(256)][d(192)] bf16, row 255 zeroed ----
__global__ __launch_bounds__(256) void prep_k(const float* __restrict__ k,
                                              __bf16* __restrict__ kb) {
    const int t  = blockIdx.x * 256 + threadIdx.x;   // 768 blocks: 196608 threads x 8 elems
    const int e0 = t * 8;
    const int row = e0 / D_;        // (b*QH+h)*256 + n
    const int d0  = e0 % D_;
    const int n   = row & 255;
    const int bh  = row >> 8;
    const int b   = bh >> 4, h = bh & 15;
    bf16x8 out;
    if (n < N_) {
        const float* src = k + ((size_t)((b * N_ + n) * QH_ + h)) * D_ + d0;
        f32x4 s0 = *(const f32x4*)src;
        f32x4 s1 = *(const f32x4*)(src + 4);
        out[0]=(__bf16)s0[0]; out[1]=(__bf16)s0[1]; out[2]=(__bf16)s0[2]; out[3]=(__bf16)s0[3];
        out[4]=(__bf16)s1[0]; out[5]=(__bf16)s1[1]; out[6]=(__bf16)s1[2]; out[7]=(__bf16)s1[3];
    } else {
        #pragma unroll
        for (int e = 0; e < 8; ++e) out[e] = (__bf16)0.f;
    }
    *(bf16x8*)(kb + (size_t)row * D_ + d0) = out;
}

// ---- pre-pass 2: vt[b][h][vd][n(256)] bf16 transposed, col 255 zeroed ----
__global__ __launch_bounds__(256) void prep_v(const float* __restrict__ v,
                                              __bf16* __restrict__ vt) {
    const int n  = threadIdx.x;          // 0..255
    const int r  = blockIdx.x;           // (b*QH+h)*128 + vd ; 4096 blocks
    const int vd = r & 127;
    const int bh = r >> 7;
    const int b  = bh >> 4, h = bh & 15;
    float val = 0.f;
    if (n < N_) val = v[((size_t)((b * N_ + n) * QH_ + h)) * VD_ + vd];
    vt[(size_t)r * NP_ + n] = (__bf16)val;
}

// ---- main kernel ----
__global__ __launch_bounds__(256, 2) void cattn_kernel(
    const float* __restrict__ q, const __bf16* __restrict__ kb,
    const __bf16* __restrict__ vt, float* __restrict__ o_out,
    float* __restrict__ p_out)
{
    const float scale = 0.07216878364870322f; // 192^-0.5
    const int bid = blockIdx.x;
    const int ib  = bid & 63;          // q-block within head
    const int h   = (bid >> 6) & 15;
    const int b   = bid >> 10;
    const int bh  = b * QH_ + h;
    const int i0  = ib << 6;

    const int tid  = threadIdx.x;
    const int lane = tid & 63;
    const int wid  = tid >> 6;
    const int g    = lane >> 4;   // quarter-wave group 0..3
    const int c16  = lane & 15;
    const int iw   = i0 + wid * 16;   // this wave's first q row

    __shared__ __bf16 pbuf[4][16][264];

    // ---- load Q fragments (16 rows x 192) ----
    bf16x8 aq[6];
    {
        const int qi = iw + c16;
        const float* qrow = q + ((size_t)((b * M_ + qi) * QH_ + h)) * D_;
        #pragma unroll
        for (int s = 0; s < 6; ++s) {
            const f32x4* qp = (const f32x4*)(qrow + s * 32 + g * 8);
            f32x4 q0 = qp[0], q1 = qp[1];
            bf16x8 a;
            a[0]=(__bf16)q0[0]; a[1]=(__bf16)q0[1]; a[2]=(__bf16)q0[2]; a[3]=(__bf16)q0[3];
            a[4]=(__bf16)q1[0]; a[5]=(__bf16)q1[1]; a[6]=(__bf16)q1[2]; a[7]=(__bf16)q1[3];
            aq[s] = a;
        }
    }

    int jt_any = (iw >= 16) ? ((iw - 16) >> 8) : -1;
    if (jt_any > 15) jt_any = 15;

    // ---- S = Q K^T ----
    const __bf16* kbh = kb + (size_t)bh * NP_ * D_ + (size_t)c16 * D_ + g * 8;
    f32x4 sacc[16];
    #pragma unroll
    for (int jt = 0; jt < 16; ++jt) {
        const int n = jt * 16 + c16;
        if (jt <= jt_any) {
            f32x4 acc = {0.f, 0.f, 0.f, 0.f};
            const __bf16* krow = kbh + (size_t)jt * 16 * D_;
            #pragma unroll
            for (int s = 0; s < 6; ++s) {
                bf16x8 bb = *(const bf16x8*)(krow + s * 32);
                acc = __builtin_amdgcn_mfma_f32_16x16x32_bf16(aq[s], bb, acc, 0, 0, 0);
            }
            #pragma unroll
            for (int r = 0; r < 4; ++r) {
                const int i = iw + g * 4 + r;
                const bool ok = (i >= 16 * n + 31) && (n < N_);
                acc[r] = ok ? acc[r] * scale : -1e30f;
            }
            sacc[jt] = acc;
        } else {
            sacc[jt] = (f32x4){-1e30f, -1e30f, -1e30f, -1e30f};
        }
    }

    // ---- row softmax ----
    float inv_l[4];
    #pragma unroll
    for (int r = 0; r < 4; ++r) {
        float m = sacc[0][r];
        #pragma unroll
        for (int jt = 1; jt < 16; ++jt) m = fmaxf(m, sacc[jt][r]);
        m = fmaxf(m, __shfl_xor(m, 1));
        m = fmaxf(m, __shfl_xor(m, 2));
        m = fmaxf(m, __shfl_xor(m, 4));
        m = fmaxf(m, __shfl_xor(m, 8));
        float sum = 0.f;
        #pragma unroll
        for (int jt = 0; jt < 16; ++jt) {
            float e = __expf(sacc[jt][r] - m);
            if (jt == 15 && c16 == 15) e = 0.f;   // col 255 doesn't exist
            sacc[jt][r] = e;
            sum += e;
        }
        sum += __shfl_xor(sum, 1);
        sum += __shfl_xor(sum, 2);
        sum += __shfl_xor(sum, 4);
        sum += __shfl_xor(sum, 8);
        inv_l[r] = 1.0f / sum;
    }

    // ---- write p (fp32 global + bf16 LDS) ----
    #pragma unroll
    for (int jt = 0; jt < 16; ++jt) {
        const int n = jt * 16 + c16;
        #pragma unroll
        for (int r = 0; r < 4; ++r) {
            const int i = iw + g * 4 + r;
            const float pv = sacc[jt][r] * inv_l[r];
            if (n < N_) {
                p_out[(size_t)(bh * M_ + i) * N_ + n] = pv;
            }
            pbuf[wid][g * 4 + r][jt * 16 + c16] = (__bf16)pv;
        }
    }

    __syncthreads();

    // ---- O = P V ----
    f32x4 oacc[8];
    #pragma unroll
    for (int t = 0; t < 8; ++t) oacc[t] = (f32x4){0.f, 0.f, 0.f, 0.f};

    const __bf16* vth = vt + (size_t)bh * VD_ * NP_ + (size_t)c16 * NP_ + g * 8;
    const int c_lim = (jt_any < 0) ? 0 : ((jt_any + 2) >> 1);
    #pragma unroll
    for (int c = 0; c < 8; ++c) {
        if (c < c_lim) {
            bf16x8 pa = *(const bf16x8*)(&pbuf[wid][c16][c * 32 + g * 8]);
            #pragma unroll
            for (int vdt = 0; vdt < 8; ++vdt) {
                bf16x8 vb = *(const bf16x8*)(vth + (size_t)vdt * 16 * NP_ + c * 32);
                oacc[vdt] = __builtin_amdgcn_mfma_f32_16x16x32_bf16(pa, vb, oacc[vdt], 0, 0, 0);
            }
        }
    }

    // ---- write O ----
    #pragma unroll
    for (int vdt = 0; vdt < 8; ++vdt) {
        #pragma unroll
        for (int r = 0; r < 4; ++r) {
            const int i = iw + g * 4 + r;
            const float val = (i < 31) ? 0.f : oacc[vdt][r];
            o_out[(size_t)((b * M_ + i) * QH_ + h) * VD_ + vdt * 16 + c16] = val;
        }
    }
}

extern "C" void kernel_launch(void* const* d_in, const int* in_sizes, int n_in,
                              void* d_out, int out_size, void* d_ws, size_t ws_size,
                              hipStream_t stream) {
    (void)in_sizes; (void)n_in; (void)ws_size; (void)out_size;
    const float* q = (const float*)d_in[0];
    const float* k = (const float*)d_in[1];
    const float* v = (const float*)d_in[2];
    float* o_out = (float*)d_out;
    float* p_out = o_out + (size_t)B_ * M_ * QH_ * VD_;   // tuple: (o, p) flat

    __bf16* kb = (__bf16*)d_ws;                                  // 2*16*256*192*2 = 3.145 MB
    __bf16* vt = kb + (size_t)B_ * QH_ * NP_ * D_;               // 2*16*128*256*2 = 2.097 MB

    prep_k<<<dim3((B_ * QH_ * NP_ * D_ / 8 + 255) / 256), dim3(256), 0, stream>>>(k, kb);
    prep_v<<<dim3(B_ * QH_ * VD_), dim3(256), 0, stream>>>(v, vt);

    dim3 grid(B_ * QH_ * (M_ / 64));   // 2048 blocks
    dim3 block(256);                    // 4 waves x 16 rows
    cattn_kernel<<<grid, block, 0, stream>>>(q, kb, vt, o_out, p_out);
}